// Round 3
// baseline (71.219 us; speedup 1.0000x reference)
//
#include <hip/hip_runtime.h>

#define SGRID 14
static constexpr float INV_S = 1.0f / 14.0f;

// address-space-qualified pointer types for global_load_lds
typedef const unsigned int __attribute__((address_space(1)))* gas_ptr;
typedef unsigned int __attribute__((address_space(3)))* las_ptr;

__device__ __forceinline__ void gld_lds4(const void* g, void* l) {
    // async 4B/lane global -> LDS DMA; LDS dest = wave-uniform base + lane*4
    __builtin_amdgcn_global_load_lds((gas_ptr)g, (las_ptr)l, 4, 0, 0);
}

__device__ __forceinline__ float cell_loss(const float* p, const float* t) {
    float tconf = t[4];
    float obj   = (tconf == 1.0f) ? 1.0f : 0.0f;
    float noobj = (tconf == 0.0f) ? 1.0f : 0.0f;

    float d4 = p[4] - t[4];
    float d9 = p[9] - t[9];
    float no_object_loss = noobj * (d4 * d4 + d9 * d9);

    float class_loss = 0.0f;
    #pragma unroll
    for (int c = 10; c < 30; ++c) { float d = p[c] - t[c]; class_loss += d * d; }
    class_loss *= obj;

    float iou[2];
    #pragma unroll
    for (int b = 0; b < 2; ++b) {
        int o = b * 5;
        float pcx = p[o] * INV_S, pcy = p[o+1] * INV_S, pw = p[o+2], ph = p[o+3];
        float tcx = t[o] * INV_S, tcy = t[o+1] * INV_S, tw = t[o+2], th = t[o+3];
        float px0 = pcx - 0.5f * pw, py0 = pcy - 0.5f * ph;
        float px1 = pcx + 0.5f * pw, py1 = pcy + 0.5f * ph;
        float tx0 = tcx - 0.5f * tw, ty0 = tcy - 0.5f * th;
        float tx1 = tcx + 0.5f * tw, ty1 = tcy + 0.5f * th;
        float lx = fmaxf(px0, tx0), ly = fmaxf(py0, ty0);
        float rx = fminf(px1, tx1), ry = fminf(py1, ty1);
        float wx = fmaxf(rx - lx, 0.0f), wy = fmaxf(ry - ly, 0.0f);
        float inter = wx * wy;
        float ap = (px1 - px0) * (py1 - py0);
        float at = (tx1 - tx0) * (ty1 - ty0);
        float denom = ap + at - inter;
        iou[b] = (denom > 0.0f) ? (inter / denom) : 0.0f;
    }

    bool pick1 = (iou[0] <= iou[1]);
    float chosen = pick1 ? iou[1] : iou[0];
    int o = pick1 ? 5 : 0;

    float dx = p[o]   - t[o];
    float dy = p[o+1] - t[o+1];
    float dw = sqrtf(p[o+2]) - sqrtf(t[o+2]);
    float dh = sqrtf(p[o+3]) - sqrtf(t[o+3]);
    float reg = dx * dx + dy * dy + dw * dw + dh * dh;

    float dconf = p[o+4] - chosen;
    float contain = dconf * dconf;

    return obj * (5.0f * reg + contain) + 0.5f * no_object_loss + class_loss;
}

// One wave (64 threads) per block. Chunk = 32 cells:
//   pred 32*30 = 960 floats + tgt 960 floats staged as 30 x 256B
//   global_load_lds (4B/lane). Double-buffered (15.36 KB/block -> 10 blocks/CU).
//   Compute: lanes 0..31, one cell each.
__global__ __launch_bounds__(64) void yolo_loss_kernel(
    const float* __restrict__ pred, const float* __restrict__ tgt,
    float* __restrict__ out, int ncells, int nchunks, float invN)
{
    __shared__ float sbuf[2][1920];   // 2 x 7680 B
    const int lane = threadIdx.x;     // 0..63
    float sum = 0.0f;

    int chunk  = blockIdx.x;
    const int stride = gridDim.x;
    int buf = 0;

    auto stage = [&](int c, int b) {
        const float* pg = pred + (size_t)c * 960;
        const float* tg = tgt  + (size_t)c * 960;
        #pragma unroll
        for (int j = 0; j < 15; ++j) {
            gld_lds4((const void*)(pg + j * 64 + lane), (void*)&sbuf[b][j * 64]);
            gld_lds4((const void*)(tg + j * 64 + lane), (void*)&sbuf[b][960 + j * 64]);
        }
    };

    if (chunk < nchunks) stage(chunk, 0);

    while (chunk < nchunks) {
        int next = chunk + stride;
        if (next < nchunks) {
            // previous compute's ds_reads fully drained before overwriting buf^1
            asm volatile("s_waitcnt lgkmcnt(0)" ::: "memory");
            stage(next, buf ^ 1);
            // wait only for the CURRENT buffer's 30 DMAs (in-order completion)
            asm volatile("s_waitcnt vmcnt(30)" ::: "memory");
        } else {
            asm volatile("s_waitcnt vmcnt(0)" ::: "memory");
        }

        if (lane < 32) {
            const float* base = &sbuf[buf][0];
            const float2* cp2 = (const float2*)(base + lane * 30);
            const float2* ct2 = (const float2*)(base + 960 + lane * 30);
            float p[30], t[30];
            #pragma unroll
            for (int j = 0; j < 15; ++j) { float2 v = cp2[j]; p[2*j] = v.x; p[2*j+1] = v.y; }
            #pragma unroll
            for (int j = 0; j < 15; ++j) { float2 v = ct2[j]; t[2*j] = v.x; t[2*j+1] = v.y; }
            sum += cell_loss(p, t);
        }

        buf ^= 1;
        chunk = next;
    }

    // remainder cells (ncells % 32) — direct global path, block 0 only
    int rem = ncells - nchunks * 32;
    if (rem > 0 && blockIdx.x == 0 && lane < rem) {
        int cell = nchunks * 32 + lane;
        const float2* p2 = (const float2*)(pred + (size_t)cell * 30);
        const float2* t2 = (const float2*)(tgt  + (size_t)cell * 30);
        float p[30], t[30];
        #pragma unroll
        for (int j = 0; j < 15; ++j) { float2 v = p2[j]; p[2*j] = v.x; p[2*j+1] = v.y; }
        #pragma unroll
        for (int j = 0; j < 15; ++j) { float2 v = t2[j]; t[2*j] = v.x; t[2*j+1] = v.y; }
        sum += cell_loss(p, t);
    }

    #pragma unroll
    for (int off = 32; off > 0; off >>= 1) sum += __shfl_down(sum, off, 64);
    if (lane == 0) atomicAdd(out, sum * invN);
}

extern "C" void kernel_launch(void* const* d_in, const int* in_sizes, int n_in,
                              void* d_out, int out_size, void* d_ws, size_t ws_size,
                              hipStream_t stream) {
    const float* pred = (const float*)d_in[0];
    const float* tgt  = (const float*)d_in[1];
    float* out = (float*)d_out;

    int ncells  = in_sizes[0] / 30;               // N * S * S
    int N       = ncells / (SGRID * SGRID);
    float invN  = 1.0f / (float)N;
    int nchunks = ncells / 32;

    hipMemsetAsync(out, 0, sizeof(float) * (out_size > 0 ? out_size : 1), stream);

    int blocks = nchunks < 1 ? 1 : (nchunks < 2560 ? nchunks : 2560);
    yolo_loss_kernel<<<blocks, 64, 0, stream>>>(pred, tgt, out, ncells, nchunks, invN);
}

// Round 4
// 41.359 us; speedup vs baseline: 1.7219x; 1.7219x over previous
//
#include <hip/hip_runtime.h>

#define SGRID 14
static constexpr float INV_S = 1.0f / 14.0f;

// address-space-qualified pointer types for global_load_lds
typedef const unsigned int __attribute__((address_space(1)))* gas_ptr;
typedef unsigned int __attribute__((address_space(3)))* las_ptr;

__device__ __forceinline__ void gld_lds16(const void* g, void* l) {
    // async 16B/lane global -> LDS DMA; LDS dest = wave-uniform base + lane*16
    __builtin_amdgcn_global_load_lds((gas_ptr)g, (las_ptr)l, 16, 0, 0);
}

__device__ __forceinline__ float cell_loss(const float* p, const float* t) {
    float tconf = t[4];
    float obj   = (tconf == 1.0f) ? 1.0f : 0.0f;
    float noobj = (tconf == 0.0f) ? 1.0f : 0.0f;

    float d4 = p[4] - t[4];
    float d9 = p[9] - t[9];
    float no_object_loss = noobj * (d4 * d4 + d9 * d9);

    float class_loss = 0.0f;
    #pragma unroll
    for (int c = 10; c < 30; ++c) { float d = p[c] - t[c]; class_loss += d * d; }
    class_loss *= obj;

    float iou[2];
    #pragma unroll
    for (int b = 0; b < 2; ++b) {
        int o = b * 5;
        float pcx = p[o] * INV_S, pcy = p[o+1] * INV_S, pw = p[o+2], ph = p[o+3];
        float tcx = t[o] * INV_S, tcy = t[o+1] * INV_S, tw = t[o+2], th = t[o+3];
        float px0 = pcx - 0.5f * pw, py0 = pcy - 0.5f * ph;
        float px1 = pcx + 0.5f * pw, py1 = pcy + 0.5f * ph;
        float tx0 = tcx - 0.5f * tw, ty0 = tcy - 0.5f * th;
        float tx1 = tcx + 0.5f * tw, ty1 = tcy + 0.5f * th;
        float lx = fmaxf(px0, tx0), ly = fmaxf(py0, ty0);
        float rx = fminf(px1, tx1), ry = fminf(py1, ty1);
        float wx = fmaxf(rx - lx, 0.0f), wy = fmaxf(ry - ly, 0.0f);
        float inter = wx * wy;
        float ap = (px1 - px0) * (py1 - py0);
        float at = (tx1 - tx0) * (ty1 - ty0);
        float denom = ap + at - inter;
        iou[b] = (denom > 0.0f) ? (inter / denom) : 0.0f;
    }

    bool pick1 = (iou[0] <= iou[1]);
    float chosen = pick1 ? iou[1] : iou[0];
    int o = pick1 ? 5 : 0;

    float dx = p[o]   - t[o];
    float dy = p[o+1] - t[o+1];
    float dw = sqrtf(p[o+2]) - sqrtf(t[o+2]);
    float dh = sqrtf(p[o+3]) - sqrtf(t[o+3]);
    float reg = dx * dx + dy * dy + dw * dw + dh * dh;

    float dconf = p[o+4] - chosen;
    float contain = dconf * dconf;

    return obj * (5.0f * reg + contain) + 0.5f * no_object_loss + class_loss;
}

// 4-wave (256-thread) blocks, m97-style staging. Chunk = 256 cells:
//   pred 1920 float4 + tgt 1920 float4 = 60 x 1KB global_load_lds dwordx4,
//   15 per wave. Single 61.4KB buffer -> 2 blocks/CU; the vmcnt(0) drain at
//   the barrier is overlapped by the other resident block.
__global__ __launch_bounds__(256) void yolo_loss_kernel(
    const float* __restrict__ pred, const float* __restrict__ tgt,
    float* __restrict__ out, int ncells, int nchunks, float invN)
{
    __shared__ float4 sbuf[3840];     // 61440 B: pred f4 [0,1920), tgt f4 [1920,3840)
    __shared__ float wpart[4];
    const int tid  = threadIdx.x;
    const int lane = tid & 63;
    const int wv   = tid >> 6;
    float sum = 0.0f;

    for (int chunk = blockIdx.x; chunk < nchunks; chunk += gridDim.x) {
        const float4* p4 = (const float4*)(pred + (size_t)chunk * 7680);
        const float4* t4 = (const float4*)(tgt  + (size_t)chunk * 7680);
        const int j0 = wv * 15;
        #pragma unroll
        for (int j = 0; j < 15; ++j) {
            int jj = j0 + j;                               // 0..59 across waves
            // DMA granularity aligns with the pred/tgt seam: jj<30 -> pred
            const float4* src = (jj < 30) ? (p4 + jj * 64) : (t4 + (jj - 30) * 64);
            gld_lds16((const void*)(src + lane), (void*)&sbuf[jj * 64]);
        }
        __syncthreads();   // compiler drains vmcnt+lgkmcnt here; data visible

        {
            const float* base = (const float*)sbuf;
            const float2* cp2 = (const float2*)(base + tid * 30);
            const float2* ct2 = (const float2*)(base + 7680 + tid * 30);
            float p[30], t[30];
            #pragma unroll
            for (int j = 0; j < 15; ++j) { float2 v = cp2[j]; p[2*j] = v.x; p[2*j+1] = v.y; }
            #pragma unroll
            for (int j = 0; j < 15; ++j) { float2 v = ct2[j]; t[2*j] = v.x; t[2*j+1] = v.y; }
            sum += cell_loss(p, t);
        }
        __syncthreads();   // buffer safe to overwrite next iteration
    }

    // remainder cells (ncells % 256) — direct global path, block 0 only
    int rem = ncells - nchunks * 256;
    if (rem > 0 && blockIdx.x == 0 && tid < rem) {
        int cell = nchunks * 256 + tid;
        const float2* p2 = (const float2*)(pred + (size_t)cell * 30);
        const float2* t2 = (const float2*)(tgt  + (size_t)cell * 30);
        float p[30], t[30];
        #pragma unroll
        for (int j = 0; j < 15; ++j) { float2 v = p2[j]; p[2*j] = v.x; p[2*j+1] = v.y; }
        #pragma unroll
        for (int j = 0; j < 15; ++j) { float2 v = t2[j]; t[2*j] = v.x; t[2*j+1] = v.y; }
        sum += cell_loss(p, t);
    }

    #pragma unroll
    for (int off = 32; off > 0; off >>= 1) sum += __shfl_down(sum, off, 64);
    if (lane == 0) wpart[wv] = sum;
    __syncthreads();
    if (tid == 0)
        atomicAdd(out, (wpart[0] + wpart[1] + wpart[2] + wpart[3]) * invN);
}

extern "C" void kernel_launch(void* const* d_in, const int* in_sizes, int n_in,
                              void* d_out, int out_size, void* d_ws, size_t ws_size,
                              hipStream_t stream) {
    const float* pred = (const float*)d_in[0];
    const float* tgt  = (const float*)d_in[1];
    float* out = (float*)d_out;

    int ncells  = in_sizes[0] / 30;               // N * S * S
    int N       = ncells / (SGRID * SGRID);
    float invN  = 1.0f / (float)N;
    int nchunks = ncells / 256;

    hipMemsetAsync(out, 0, sizeof(float) * (out_size > 0 ? out_size : 1), stream);

    int blocks = nchunks < 1 ? 1 : (nchunks < 512 ? nchunks : 512);
    yolo_loss_kernel<<<blocks, 256, 0, stream>>>(pred, tgt, out, ncells, nchunks, invN);
}